// Round 1
// baseline (818.925 us; speedup 1.0000x reference)
//
#include <hip/hip_runtime.h>

#define D128 128
#define TT 6
#define KTOT 896            // 6*128 (mean types) + 128 (x @ sum(W_r))
#define BM 128
#define BK 32
#define LN_EPS 1e-5f

// --- prep: W_rs = sum_t W_r[t], bias_total = sum_t (b[t] + emb[t]) ---
__global__ void prep_kernel(const float* __restrict__ W_r, const float* __restrict__ b,
                            const float* __restrict__ emb,
                            float* __restrict__ W_rs, float* __restrict__ bias_total) {
    int i = blockIdx.x * 256 + threadIdx.x;
    if (i < D128 * D128) {
        float s = 0.f;
#pragma unroll
        for (int t = 0; t < TT; ++t) s += W_r[t * D128 * D128 + i];
        W_rs[i] = s;
    } else if (i < D128 * D128 + D128) {
        int o = i - D128 * D128;
        float s = 0.f;
#pragma unroll
        for (int t = 0; t < TT; ++t) s += b[t * D128 + o] + emb[t * D128 + o];
        bias_total[o] = s;
    }
}

// --- scatter: one wave (64 lanes) per edge; float2 per lane -> 128 floats ---
__global__ void scatter_kernel(const float* __restrict__ x, const int* __restrict__ ei,
                               const int* __restrict__ et, float* __restrict__ sums,
                               float* __restrict__ cnt, int E) {
    int gid = blockIdx.x * blockDim.x + threadIdx.x;
    int e = gid >> 6;
    int lane = gid & 63;
    if (e >= E) return;
    int src = ei[e];
    int dst = ei[E + e];
    int t = et[e];
    float2 v = *(const float2*)(x + (size_t)src * D128 + lane * 2);
    float* base = sums + ((size_t)dst * TT + t) * D128 + lane * 2;
    atomicAdd(base + 0, v.x);
    atomicAdd(base + 1, v.y);
    if (lane == 0) atomicAdd(cnt + (size_t)dst * TT + t, 1.0f);
}

// --- cnt -> 1/max(cnt,1) in place ---
__global__ void invcnt_kernel(float* __restrict__ cnt, int n) {
    int i = blockIdx.x * blockDim.x + threadIdx.x;
    if (i < n) cnt[i] = 1.0f / fmaxf(cnt[i], 1.0f);
}

// --- fused GEMM (M=N_nodes, N=128, K=896) + LayerNorm + ReLU ---
// A[n, k]: k in [0,768): mean[n, k/128, k%128] = sums * invcnt (fused at load)
//          k in [768,896): x[n, k-768]
// B[k, o]: k in [0,768): W_l flat (768,128);  k in [768,896): W_rs
__launch_bounds__(256)
__global__ void gemm_ln_kernel(const float* __restrict__ x, const float* __restrict__ sums,
                               const float* __restrict__ invcnt, const float* __restrict__ W_l,
                               const float* __restrict__ W_rs, const float* __restrict__ bias_total,
                               const float* __restrict__ gamma, const float* __restrict__ beta,
                               float* __restrict__ out, int N) {
    __shared__ float Ast[BK][BM];    // transposed A tile: Ast[k][m]
    __shared__ float Bs[BK][D128];   // B tile row-major

    int tid = threadIdx.x;
    int rg = tid >> 4, cg = tid & 15;       // 16x16 thread grid
    int row0 = rg * 8, col0 = cg * 8;       // 8x8 micro-tile
    int block_row = blockIdx.x * BM;

    // A-load mapping: row lm, 16 contiguous cols starting at lc
    int lm = tid >> 1;
    int lc = (tid & 1) * 16;
    int node = block_row + lm;
    int nodec = node < N ? node : N - 1;    // clamp for tail block (stores masked)

    // B-load mapping: row rb, 16 contiguous cols at cb
    int rb = tid >> 3;
    int cb = (tid & 7) * 16;

    float acc[8][8];
#pragma unroll
    for (int i = 0; i < 8; i++)
#pragma unroll
        for (int j = 0; j < 8; j++) acc[i][j] = 0.f;

#pragma unroll 1
    for (int kk = 0; kk < KTOT; kk += BK) {
        int t = kk >> 7;   // BK=32 slab lies within one type
        const float* ap;
        float scale;
        if (t == TT) {
            ap = x + (size_t)nodec * D128 + ((kk & 127) + lc);
            scale = 1.0f;
        } else {
            ap = sums + ((size_t)nodec * TT + t) * D128 + ((kk & 127) + lc);
            scale = invcnt[nodec * TT + t];
        }
        float4 a0 = ((const float4*)ap)[0];
        float4 a1 = ((const float4*)ap)[1];
        float4 a2 = ((const float4*)ap)[2];
        float4 a3 = ((const float4*)ap)[3];

        int kb = kk + rb;
        const float* bp = (kb < TT * D128) ? (W_l + (size_t)kb * D128 + cb)
                                           : (W_rs + (size_t)(kb - TT * D128) * D128 + cb);
        float4 b0 = ((const float4*)bp)[0];
        float4 b1 = ((const float4*)bp)[1];
        float4 b2 = ((const float4*)bp)[2];
        float4 b3 = ((const float4*)bp)[3];

        __syncthreads();   // previous iteration's LDS reads done
        Ast[lc + 0][lm] = a0.x * scale;  Ast[lc + 1][lm] = a0.y * scale;
        Ast[lc + 2][lm] = a0.z * scale;  Ast[lc + 3][lm] = a0.w * scale;
        Ast[lc + 4][lm] = a1.x * scale;  Ast[lc + 5][lm] = a1.y * scale;
        Ast[lc + 6][lm] = a1.z * scale;  Ast[lc + 7][lm] = a1.w * scale;
        Ast[lc + 8][lm] = a2.x * scale;  Ast[lc + 9][lm] = a2.y * scale;
        Ast[lc + 10][lm] = a2.z * scale; Ast[lc + 11][lm] = a2.w * scale;
        Ast[lc + 12][lm] = a3.x * scale; Ast[lc + 13][lm] = a3.y * scale;
        Ast[lc + 14][lm] = a3.z * scale; Ast[lc + 15][lm] = a3.w * scale;
        *(float4*)&Bs[rb][cb + 0]  = b0;
        *(float4*)&Bs[rb][cb + 4]  = b1;
        *(float4*)&Bs[rb][cb + 8]  = b2;
        *(float4*)&Bs[rb][cb + 12] = b3;
        __syncthreads();

#pragma unroll 4
        for (int k2 = 0; k2 < BK; ++k2) {
            float4 av0 = *(const float4*)&Ast[k2][row0];
            float4 av1 = *(const float4*)&Ast[k2][row0 + 4];
            float4 bv0 = *(const float4*)&Bs[k2][col0];
            float4 bv1 = *(const float4*)&Bs[k2][col0 + 4];
            float a[8] = {av0.x, av0.y, av0.z, av0.w, av1.x, av1.y, av1.z, av1.w};
            float bb[8] = {bv0.x, bv0.y, bv0.z, bv0.w, bv1.x, bv1.y, bv1.z, bv1.w};
#pragma unroll
            for (int i = 0; i < 8; i++)
#pragma unroll
                for (int j = 0; j < 8; j++)
                    acc[i][j] = fmaf(a[i], bb[j], acc[i][j]);
        }
    }

    // epilogue: + bias, LayerNorm over D (16-lane cluster holds a full row), ReLU
    float g8[8], bt8[8], bs8[8];
#pragma unroll
    for (int j = 0; j < 8; j++) {
        bs8[j] = bias_total[col0 + j];
        g8[j]  = gamma[col0 + j];
        bt8[j] = beta[col0 + j];
    }
#pragma unroll
    for (int i = 0; i < 8; i++) {
        float s = 0.f, s2 = 0.f;
#pragma unroll
        for (int j = 0; j < 8; j++) {
            float h = acc[i][j] + bs8[j];
            acc[i][j] = h;
            s += h;
            s2 += h * h;
        }
#pragma unroll
        for (int off = 8; off >= 1; off >>= 1) {
            s  += __shfl_xor(s, off, 16);
            s2 += __shfl_xor(s2, off, 16);
        }
        float mu  = s * (1.0f / 128.0f);
        float var = s2 * (1.0f / 128.0f) - mu * mu;
        float rstd = rsqrtf(var + LN_EPS);
        int orow = block_row + row0 + i;
        if (orow < N) {
            float o[8];
#pragma unroll
            for (int j = 0; j < 8; j++) {
                float y = (acc[i][j] - mu) * rstd * g8[j] + bt8[j];
                o[j] = fmaxf(y, 0.f);
            }
            float* op = out + (size_t)orow * D128 + col0;
            *(float4*)(op + 0) = make_float4(o[0], o[1], o[2], o[3]);
            *(float4*)(op + 4) = make_float4(o[4], o[5], o[6], o[7]);
        }
    }
}

extern "C" void kernel_launch(void* const* d_in, const int* in_sizes, int n_in,
                              void* d_out, int out_size, void* d_ws, size_t ws_size,
                              hipStream_t stream) {
    const float* x     = (const float*)d_in[0];
    const int*   ei    = (const int*)d_in[1];
    const int*   et    = (const int*)d_in[2];
    const float* W_l   = (const float*)d_in[3];
    const float* W_r   = (const float*)d_in[4];
    const float* b     = (const float*)d_in[5];
    const float* emb   = (const float*)d_in[6];
    const float* gamma = (const float*)d_in[7];
    const float* beta  = (const float*)d_in[8];

    int N = in_sizes[0] / D128;
    int E = in_sizes[2];

    float* sums       = (float*)d_ws;                      // N*T*D
    float* cnt        = sums + (size_t)N * TT * D128;      // N*T
    float* W_rs       = cnt + (size_t)N * TT;              // 128*128
    float* bias_total = W_rs + D128 * D128;                // 128

    size_t zero_bytes = ((size_t)N * TT * D128 + (size_t)N * TT) * sizeof(float);
    hipMemsetAsync(d_ws, 0, zero_bytes, stream);

    prep_kernel<<<(D128 * D128 + D128 + 255) / 256, 256, 0, stream>>>(W_r, b, emb, W_rs, bias_total);

    int scatter_threads = E * 64;
    scatter_kernel<<<(scatter_threads + 255) / 256, 256, 0, stream>>>(x, ei, et, sums, cnt, E);

    invcnt_kernel<<<(N * TT + 255) / 256, 256, 0, stream>>>(cnt, N * TT);

    gemm_ln_kernel<<<(N + BM - 1) / BM, 256, 0, stream>>>(x, sums, cnt, W_l, W_rs, bias_total,
                                                          gamma, beta, (float*)d_out, N);
}

// Round 2
// 422.950 us; speedup vs baseline: 1.9362x; 1.9362x over previous
//
#include <hip/hip_runtime.h>

#define TT 6
#define D 128
#define PITCH 136          // bf16 elems per LDS/global B row (128 + 8 pad)
#define BM 128
#define SCAN_BLK 2048      // 256 threads x 8 elems
#define LN_EPS 1e-5f

typedef __bf16 bf16x8 __attribute__((ext_vector_type(8)));
typedef float f32x4 __attribute__((ext_vector_type(4)));

__device__ __forceinline__ unsigned short f2bf(float f) {
    unsigned int u = __float_as_uint(f);
    unsigned int r = (u + 0x7FFFu + ((u >> 16) & 1u)) >> 16;  // RNE
    return (unsigned short)r;
}

// --- prep: WlT[t][n][k] = bf16(W_l[t][k][n]) for t<6; slab 6 = sum_t W_r[t] transposed.
//     bias_total[o] = sum_t (b[t][o] + emb[t][o])
__global__ void prep_kernel(const float* __restrict__ W_l, const float* __restrict__ W_r,
                            const float* __restrict__ b, const float* __restrict__ emb,
                            unsigned short* __restrict__ WlT, float* __restrict__ bias_total) {
    int i = blockIdx.x * 256 + threadIdx.x;
    const int per = D * PITCH;
    if (i < 7 * per) {
        int t = i / per, r = i % per, n = r / PITCH, k = r % PITCH;
        float f = 0.f;
        if (k < D) {
            if (t < TT) {
                f = W_l[((size_t)t * D + k) * D + n];
            } else {
#pragma unroll
                for (int tt = 0; tt < TT; ++tt) f += W_r[((size_t)tt * D + k) * D + n];
            }
        }
        WlT[i] = f2bf(f);
    } else if (i < 7 * per + D) {
        int o = i - 7 * per;
        float s = 0.f;
#pragma unroll
        for (int t = 0; t < TT; ++t) s += b[t * D + o] + emb[t * D + o];
        bias_total[o] = s;
    }
}

// --- histogram of seg = dst*6 + t ---
__global__ void hist_kernel(const int* __restrict__ ei, const int* __restrict__ et,
                            int* __restrict__ hist, int E) {
    int e = blockIdx.x * 256 + threadIdx.x;
    if (e >= E) return;
    atomicAdd(&hist[ei[E + e] * TT + et[e]], 1);
}

// --- exclusive scan, block handles 2048 elems; also emits per-block totals ---
__global__ void scan1_kernel(const int* __restrict__ in, int* __restrict__ out,
                             int* __restrict__ bsum, int S) {
    __shared__ int wsum[4];
    __shared__ int woff[4];
    int tid = threadIdx.x;
    int base = blockIdx.x * SCAN_BLK + tid * 8;
    int v[8];
    int ts = 0;
#pragma unroll
    for (int j = 0; j < 8; ++j) {
        v[j] = (base + j < S) ? in[base + j] : 0;
        ts += v[j];
    }
    int lane = tid & 63, wave = tid >> 6;
    int inc = ts;
#pragma unroll
    for (int o = 1; o < 64; o <<= 1) {
        int n = __shfl_up(inc, o);
        if (lane >= o) inc += n;
    }
    if (lane == 63) wsum[wave] = inc;
    __syncthreads();
    if (tid == 0) {
        int r = 0;
#pragma unroll
        for (int w = 0; w < 4; ++w) { int t = wsum[w]; woff[w] = r; r += t; }
        bsum[blockIdx.x] = r;
    }
    __syncthreads();
    int run = woff[wave] + inc - ts;   // thread-exclusive prefix
#pragma unroll
    for (int j = 0; j < 8; ++j) {
        if (base + j < S) out[base + j] = run;
        run += v[j];
    }
}

// --- add block offsets, produce final off[] and a mutable cursor copy ---
__global__ void scan3_kernel(int* __restrict__ off, int* __restrict__ cursor,
                             const int* __restrict__ bscan, int S, int E) {
    int tid = threadIdx.x;
    int base = blockIdx.x * SCAN_BLK + tid * 8;
    int add = bscan[blockIdx.x];
#pragma unroll
    for (int j = 0; j < 8; ++j) {
        int i = base + j;
        if (i < S) { int t = off[i] + add; off[i] = t; cursor[i] = t; }
    }
    if (blockIdx.x == 0 && tid == 0) off[S] = E;
}

// --- scatter edge src ids into segment-sorted order ---
__global__ void fill_kernel(const int* __restrict__ ei, const int* __restrict__ et,
                            int* __restrict__ cursor, int* __restrict__ sorted_src, int E) {
    int e = blockIdx.x * 256 + threadIdx.x;
    if (e >= E) return;
    int seg = ei[E + e] * TT + et[e];
    int pos = atomicAdd(&cursor[seg], 1);
    sorted_src[pos] = ei[e];
}

// --- fused: per-type mean aggregation -> bf16 MFMA GEMM -> bias+LN+ReLU ---
__launch_bounds__(256, 2)
__global__ void fused_kernel(const float* __restrict__ x, const int* __restrict__ off,
                             const int* __restrict__ sorted_src,
                             const unsigned short* __restrict__ WlT,
                             const float* __restrict__ bias_total,
                             const float* __restrict__ gamma, const float* __restrict__ beta,
                             float* __restrict__ out, int N) {
    __shared__ unsigned short As[BM * PITCH];   // A tile [m][k] bf16
    __shared__ unsigned short Bs[D * PITCH];    // B tile [n][k] bf16 (pre-transposed W)

    int tid = threadIdx.x;
    int lane = tid & 63, wave = tid >> 6;
    int q = lane >> 4, c16 = lane & 15;
    int blockRow = blockIdx.x * BM;

    f32x4 acc[2][8];
#pragma unroll
    for (int rt = 0; rt < 2; ++rt)
#pragma unroll
        for (int ct = 0; ct < 8; ++ct) acc[rt][ct] = (f32x4){0.f, 0.f, 0.f, 0.f};

#pragma unroll 1
    for (int t = 0; t < 7; ++t) {
        __syncthreads();   // previous iteration's frag reads complete

        // ---- build A tile (bf16) for this K-slab ----
        if (t < TT) {
#pragma unroll 1
            for (int i = 0; i < 32; ++i) {
                int m = wave * 32 + i;
                int node = blockRow + m;
                float ax = 0.f, ay = 0.f;
                if (node < N) {
                    int s = node * TT + t;
                    int e0 = off[s], e1 = off[s + 1];
                    int e = e0;
                    while (e + 1 < e1) {
                        int s0 = sorted_src[e], s1 = sorted_src[e + 1];
                        float2 v0 = ((const float2*)(x + (size_t)s0 * D))[lane];
                        float2 v1 = ((const float2*)(x + (size_t)s1 * D))[lane];
                        ax += v0.x + v1.x;
                        ay += v0.y + v1.y;
                        e += 2;
                    }
                    if (e < e1) {
                        int s0 = sorted_src[e];
                        float2 v0 = ((const float2*)(x + (size_t)s0 * D))[lane];
                        ax += v0.x;
                        ay += v0.y;
                    }
                    int c = e1 - e0;
                    if (c > 1) { float sc = 1.f / (float)c; ax *= sc; ay *= sc; }
                }
                unsigned int packed = (unsigned int)f2bf(ax) | ((unsigned int)f2bf(ay) << 16);
                *(unsigned int*)&As[m * PITCH + 2 * lane] = packed;
            }
        } else {
#pragma unroll 1
            for (int i = 0; i < 32; ++i) {
                int m = wave * 32 + i;
                int node = blockRow + m;
                float ax = 0.f, ay = 0.f;
                if (node < N) {
                    float2 v = ((const float2*)(x + (size_t)node * D))[lane];
                    ax = v.x; ay = v.y;
                }
                unsigned int packed = (unsigned int)f2bf(ax) | ((unsigned int)f2bf(ay) << 16);
                *(unsigned int*)&As[m * PITCH + 2 * lane] = packed;
            }
        }

        // ---- stage B tile: 17408 ushorts = 4352 uint2 ----
        {
            const uint2* bsrc = (const uint2*)(WlT + (size_t)t * D * PITCH);
            uint2* bdst = (uint2*)Bs;
#pragma unroll 1
            for (int i = tid; i < (D * PITCH) / 4; i += 256) bdst[i] = bsrc[i];
        }
        __syncthreads();

        // ---- MFMA over K=128 in 4 steps of 32 ----
#pragma unroll
        for (int ks = 0; ks < 4; ++ks) {
            int kbase = ks * 32 + q * 8;
            bf16x8 af0 = *(const bf16x8*)&As[(wave * 32 + c16) * PITCH + kbase];
            bf16x8 af1 = *(const bf16x8*)&As[(wave * 32 + 16 + c16) * PITCH + kbase];
            bf16x8 bfr[8];
#pragma unroll
            for (int ct = 0; ct < 8; ++ct)
                bfr[ct] = *(const bf16x8*)&Bs[(ct * 16 + c16) * PITCH + kbase];
#pragma unroll
            for (int ct = 0; ct < 8; ++ct) {
                acc[0][ct] = __builtin_amdgcn_mfma_f32_16x16x32_bf16(af0, bfr[ct], acc[0][ct], 0, 0, 0);
                acc[1][ct] = __builtin_amdgcn_mfma_f32_16x16x32_bf16(af1, bfr[ct], acc[1][ct], 0, 0, 0);
            }
        }
    }

    // ---- epilogue: bias + LayerNorm + ReLU ----
    float bias_c[8], g_c[8], bt_c[8];
#pragma unroll
    for (int ct = 0; ct < 8; ++ct) {
        int col = ct * 16 + c16;
        bias_c[ct] = bias_total[col];
        g_c[ct] = gamma[col];
        bt_c[ct] = beta[col];
    }
#pragma unroll
    for (int rt = 0; rt < 2; ++rt) {
#pragma unroll
        for (int reg = 0; reg < 4; ++reg) {
            float h[8];
            float s = 0.f, s2 = 0.f;
#pragma unroll
            for (int ct = 0; ct < 8; ++ct) {
                h[ct] = acc[rt][ct][reg] + bias_c[ct];
                s += h[ct];
                s2 += h[ct] * h[ct];
            }
#pragma unroll
            for (int o = 8; o >= 1; o >>= 1) {
                s  += __shfl_xor(s, o, 16);
                s2 += __shfl_xor(s2, o, 16);
            }
            float mu = s * (1.f / 128.f);
            float var = s2 * (1.f / 128.f) - mu * mu;
            float rstd = rsqrtf(var + LN_EPS);
            int row = blockRow + wave * 32 + rt * 16 + q * 4 + reg;
            if (row < N) {
#pragma unroll
                for (int ct = 0; ct < 8; ++ct) {
                    float y = (h[ct] - mu) * rstd * g_c[ct] + bt_c[ct];
                    out[(size_t)row * D + ct * 16 + c16] = fmaxf(y, 0.f);
                }
            }
        }
    }
}

extern "C" void kernel_launch(void* const* d_in, const int* in_sizes, int n_in,
                              void* d_out, int out_size, void* d_ws, size_t ws_size,
                              hipStream_t stream) {
    const float* x     = (const float*)d_in[0];
    const int*   ei    = (const int*)d_in[1];
    const int*   et    = (const int*)d_in[2];
    const float* W_l   = (const float*)d_in[3];
    const float* W_r   = (const float*)d_in[4];
    const float* b     = (const float*)d_in[5];
    const float* emb   = (const float*)d_in[6];
    const float* gamma = (const float*)d_in[7];
    const float* beta  = (const float*)d_in[8];

    int N = in_sizes[0] / D;
    int E = in_sizes[2];
    int S = N * TT;
    int NB = (S + SCAN_BLK - 1) / SCAN_BLK;

    // workspace carve
    int* hist       = (int*)d_ws;            // S
    int* off        = hist + S;              // S+1
    int* cursor     = off + S + 1;           // S
    int* bsum       = cursor + S;            // NB
    int* bscan      = bsum + NB;             // NB
    int* dummy      = bscan + NB;            // 1
    int* sorted_src = dummy + 1;             // E
    size_t ofs = (size_t)((char*)(sorted_src + E) - (char*)d_ws);
    ofs = (ofs + 15) & ~(size_t)15;
    unsigned short* WlT = (unsigned short*)((char*)d_ws + ofs);   // 7*D*PITCH bf16
    float* bias_total = (float*)(WlT + 7 * D * PITCH);            // D floats

    hipMemsetAsync(hist, 0, (size_t)S * sizeof(int), stream);

    int prep_total = 7 * D * PITCH + D;
    prep_kernel<<<(prep_total + 255) / 256, 256, 0, stream>>>(W_l, W_r, b, emb, WlT, bias_total);

    hist_kernel<<<(E + 255) / 256, 256, 0, stream>>>(ei, et, hist, E);
    scan1_kernel<<<NB, 256, 0, stream>>>(hist, off, bsum, S);
    scan1_kernel<<<1, 256, 0, stream>>>(bsum, bscan, dummy, NB);
    scan3_kernel<<<NB, 256, 0, stream>>>(off, cursor, bscan, S, E);
    fill_kernel<<<(E + 255) / 256, 256, 0, stream>>>(ei, et, cursor, sorted_src, E);

    int NBLK = (N + BM - 1) / BM;
    fused_kernel<<<NBLK, 256, 0, stream>>>(x, off, sorted_src, WlT, bias_total,
                                           gamma, beta, (float*)d_out, N);
}

// Round 3
// 315.477 us; speedup vs baseline: 2.5958x; 1.3407x over previous
//
#include <hip/hip_runtime.h>

#define TT 6
#define D 128
#define KTOT 896           // 6*128 means + 128 x-slab
#define BM 128
#define BK 64
#define SCAN_BLK 2048
#define LN_EPS 1e-5f

typedef __bf16 bf16x8 __attribute__((ext_vector_type(8)));
typedef float f32x4 __attribute__((ext_vector_type(4)));

__device__ __forceinline__ unsigned short f2bf(float f) {
    unsigned int u = __float_as_uint(f);
    unsigned int r = (u + 0x7FFFu + ((u >> 16) & 1u)) >> 16;  // RNE
    return (unsigned short)r;
}

// XOR-swizzled LDS offset (elems): row-pitch 64, 8-elem groups swizzled by row&7
__device__ __forceinline__ int lds_off(int row, int kgrp) {
    return row * 64 + ((kgrp ^ (row & 7)) << 3);
}

// --- prep: WlT[n][t*128+k] = bf16(W_l[t][k][n]); slab t=6: sum_t W_r[t][k][n].
//     bias_total[o] = sum_t (b[t][o] + emb[t][o]).  Coalesced reads.
__global__ void prep_kernel(const float* __restrict__ W_l, const float* __restrict__ W_r,
                            const float* __restrict__ b, const float* __restrict__ emb,
                            unsigned short* __restrict__ WlT, float* __restrict__ bias_total) {
    int i = blockIdx.x * 256 + threadIdx.x;
    if (i < 6 * D * D) {
        int t = i >> 14, rem = i & 16383, k = rem >> 7, n = rem & 127;
        WlT[n * KTOT + t * D + k] = f2bf(W_l[i]);
    } else if (i < 7 * D * D) {
        int rem = i & 16383, k = rem >> 7, n = rem & 127;
        float s = 0.f;
#pragma unroll
        for (int tt = 0; tt < TT; ++tt) s += W_r[tt * D * D + rem];
        WlT[n * KTOT + TT * D + k] = f2bf(s);
    } else if (i < 7 * D * D + D) {
        int o = i - 7 * D * D;
        float s = 0.f;
#pragma unroll
        for (int t = 0; t < TT; ++t) s += b[t * D + o] + emb[t * D + o];
        bias_total[o] = s;
    }
}

__global__ void hist_kernel(const int* __restrict__ ei, const int* __restrict__ et,
                            int* __restrict__ hist, int E) {
    int e = blockIdx.x * 256 + threadIdx.x;
    if (e >= E) return;
    atomicAdd(&hist[ei[E + e] * TT + et[e]], 1);
}

__global__ void scan1_kernel(const int* __restrict__ in, int* __restrict__ out,
                             int* __restrict__ bsum, int S) {
    __shared__ int wsum[4];
    __shared__ int woff[4];
    int tid = threadIdx.x;
    int base = blockIdx.x * SCAN_BLK + tid * 8;
    int v[8];
    int ts = 0;
#pragma unroll
    for (int j = 0; j < 8; ++j) {
        v[j] = (base + j < S) ? in[base + j] : 0;
        ts += v[j];
    }
    int lane = tid & 63, wave = tid >> 6;
    int inc = ts;
#pragma unroll
    for (int o = 1; o < 64; o <<= 1) {
        int n = __shfl_up(inc, o);
        if (lane >= o) inc += n;
    }
    if (lane == 63) wsum[wave] = inc;
    __syncthreads();
    if (tid == 0) {
        int r = 0;
#pragma unroll
        for (int w = 0; w < 4; ++w) { int t = wsum[w]; woff[w] = r; r += t; }
        bsum[blockIdx.x] = r;
    }
    __syncthreads();
    int run = woff[wave] + inc - ts;
#pragma unroll
    for (int j = 0; j < 8; ++j) {
        if (base + j < S) out[base + j] = run;
        run += v[j];
    }
}

__global__ void scan3_kernel(int* __restrict__ off, int* __restrict__ cursor,
                             const int* __restrict__ bscan, int S, int E) {
    int tid = threadIdx.x;
    int base = blockIdx.x * SCAN_BLK + tid * 8;
    int add = bscan[blockIdx.x];
#pragma unroll
    for (int j = 0; j < 8; ++j) {
        int i = base + j;
        if (i < S) { int t = off[i] + add; off[i] = t; cursor[i] = t; }
    }
    if (blockIdx.x == 0 && tid == 0) off[S] = E;
}

__global__ void fill_kernel(const int* __restrict__ ei, const int* __restrict__ et,
                            int* __restrict__ cursor, int* __restrict__ sorted_src, int E) {
    int e = blockIdx.x * 256 + threadIdx.x;
    if (e >= E) return;
    int seg = ei[E + e] * TT + et[e];
    int pos = atomicAdd(&cursor[seg], 1);
    sorted_src[pos] = ei[e];
}

// --- aggregate: one wave per task. Tasks [0,S): segment mean -> A[node][t*128..].
//     Tasks [S, S+N): x row -> bf16 A[node][768..895]. Massive TLP.
__global__ void aggregate_kernel(const float* __restrict__ x, const int* __restrict__ off,
                                 const int* __restrict__ sorted_src,
                                 unsigned short* __restrict__ A, int S, int N) {
    int task = blockIdx.x * 4 + (threadIdx.x >> 6);
    int lane = threadIdx.x & 63;
    if (task < S) {
        int node = task / TT, t = task - node * TT;
        int e0 = __builtin_amdgcn_readfirstlane(off[task]);
        int e1 = __builtin_amdgcn_readfirstlane(off[task + 1]);
        float ax = 0.f, ay = 0.f;
        int e = e0;
        while (e + 1 < e1) {
            int s0 = sorted_src[e], s1 = sorted_src[e + 1];
            float2 v0 = ((const float2*)(x + (size_t)s0 * D))[lane];
            float2 v1 = ((const float2*)(x + (size_t)s1 * D))[lane];
            ax += v0.x + v1.x;
            ay += v0.y + v1.y;
            e += 2;
        }
        if (e < e1) {
            int s0 = sorted_src[e];
            float2 v0 = ((const float2*)(x + (size_t)s0 * D))[lane];
            ax += v0.x;
            ay += v0.y;
        }
        int c = e1 - e0;
        if (c > 1) { float sc = 1.f / (float)c; ax *= sc; ay *= sc; }
        unsigned int packed = (unsigned int)f2bf(ax) | ((unsigned int)f2bf(ay) << 16);
        *(unsigned int*)&A[(size_t)node * KTOT + t * D + 2 * lane] = packed;
    } else if (task < S + N) {
        int node = task - S;
        float2 v = ((const float2*)(x + (size_t)node * D))[lane];
        unsigned int packed = (unsigned int)f2bf(v.x) | ((unsigned int)f2bf(v.y) << 16);
        *(unsigned int*)&A[(size_t)node * KTOT + TT * D + 2 * lane] = packed;
    }
}

// --- GEMM (M=Npad, K=896, N=128) bf16 MFMA + bias + LN + ReLU ---
__launch_bounds__(256)
__global__ void gemm_ln_kernel(const unsigned short* __restrict__ A,
                               const unsigned short* __restrict__ WlT,
                               const float* __restrict__ bias_total,
                               const float* __restrict__ gamma, const float* __restrict__ beta,
                               float* __restrict__ out, int N) {
    __shared__ unsigned short As[BM * BK];   // swizzled [m][k]
    __shared__ unsigned short Bs[D * BK];    // swizzled [n][k]

    int tid = threadIdx.x;
    int lane = tid & 63, wave = tid >> 6;
    int q = lane >> 4, c16 = lane & 15;
    int blockRow = blockIdx.x * BM;

    int lrow = tid >> 3;      // 0..31
    int lkg = tid & 7;        // 0..7  (8 bf16 per group)

    f32x4 acc[2][8];
#pragma unroll
    for (int rt = 0; rt < 2; ++rt)
#pragma unroll
        for (int ct = 0; ct < 8; ++ct) acc[rt][ct] = (f32x4){0.f, 0.f, 0.f, 0.f};

    uint4 a_reg[4], b_reg[4];
#pragma unroll
    for (int p = 0; p < 4; ++p) {
        a_reg[p] = *(const uint4*)(A + (size_t)(blockRow + p * 32 + lrow) * KTOT + lkg * 8);
        b_reg[p] = *(const uint4*)(WlT + (size_t)(p * 32 + lrow) * KTOT + lkg * 8);
    }

#pragma unroll 1
    for (int it = 0; it < KTOT / BK; ++it) {
        __syncthreads();
#pragma unroll
        for (int p = 0; p < 4; ++p) {
            *(uint4*)&As[lds_off(p * 32 + lrow, lkg)] = a_reg[p];
            *(uint4*)&Bs[lds_off(p * 32 + lrow, lkg)] = b_reg[p];
        }
        __syncthreads();

        if (it + 1 < KTOT / BK) {
            int kk = (it + 1) * BK;
#pragma unroll
            for (int p = 0; p < 4; ++p) {
                a_reg[p] = *(const uint4*)(A + (size_t)(blockRow + p * 32 + lrow) * KTOT + kk + lkg * 8);
                b_reg[p] = *(const uint4*)(WlT + (size_t)(p * 32 + lrow) * KTOT + kk + lkg * 8);
            }
        }

#pragma unroll
        for (int ks = 0; ks < 2; ++ks) {
            int kgrp = ks * 4 + q;
            int m0 = wave * 32 + c16;
            bf16x8 af0 = *(const bf16x8*)&As[lds_off(m0, kgrp)];
            bf16x8 af1 = *(const bf16x8*)&As[lds_off(m0 + 16, kgrp)];
#pragma unroll
            for (int ct = 0; ct < 8; ++ct) {
                bf16x8 bfr = *(const bf16x8*)&Bs[lds_off(ct * 16 + c16, kgrp)];
                acc[0][ct] = __builtin_amdgcn_mfma_f32_16x16x32_bf16(af0, bfr, acc[0][ct], 0, 0, 0);
                acc[1][ct] = __builtin_amdgcn_mfma_f32_16x16x32_bf16(af1, bfr, acc[1][ct], 0, 0, 0);
            }
        }
    }

    // epilogue: bias + LayerNorm + ReLU
    float bias_c[8], g_c[8], bt_c[8];
#pragma unroll
    for (int ct = 0; ct < 8; ++ct) {
        int col = ct * 16 + c16;
        bias_c[ct] = bias_total[col];
        g_c[ct] = gamma[col];
        bt_c[ct] = beta[col];
    }
#pragma unroll
    for (int rt = 0; rt < 2; ++rt) {
#pragma unroll
        for (int reg = 0; reg < 4; ++reg) {
            float h[8];
            float s = 0.f, s2 = 0.f;
#pragma unroll
            for (int ct = 0; ct < 8; ++ct) {
                h[ct] = acc[rt][ct][reg] + bias_c[ct];
                s += h[ct];
                s2 += h[ct] * h[ct];
            }
#pragma unroll
            for (int o = 8; o >= 1; o >>= 1) {
                s  += __shfl_xor(s, o, 16);
                s2 += __shfl_xor(s2, o, 16);
            }
            float mu = s * (1.f / 128.f);
            float var = s2 * (1.f / 128.f) - mu * mu;
            float rstd = rsqrtf(var + LN_EPS);
            int row = blockRow + wave * 32 + rt * 16 + q * 4 + reg;
            if (row < N) {
#pragma unroll
                for (int ct = 0; ct < 8; ++ct) {
                    float y = (h[ct] - mu) * rstd * g_c[ct] + bt_c[ct];
                    out[(size_t)row * D + ct * 16 + c16] = fmaxf(y, 0.f);
                }
            }
        }
    }
}

extern "C" void kernel_launch(void* const* d_in, const int* in_sizes, int n_in,
                              void* d_out, int out_size, void* d_ws, size_t ws_size,
                              hipStream_t stream) {
    const float* x     = (const float*)d_in[0];
    const int*   ei    = (const int*)d_in[1];
    const int*   et    = (const int*)d_in[2];
    const float* W_l   = (const float*)d_in[3];
    const float* W_r   = (const float*)d_in[4];
    const float* b     = (const float*)d_in[5];
    const float* emb   = (const float*)d_in[6];
    const float* gamma = (const float*)d_in[7];
    const float* beta  = (const float*)d_in[8];

    int N = in_sizes[0] / D;
    int E = in_sizes[2];
    int S = N * TT;
    int NB = (S + SCAN_BLK - 1) / SCAN_BLK;
    int NBLK = (N + BM - 1) / BM;
    int Npad = NBLK * BM;

    // workspace carve
    int* hist       = (int*)d_ws;            // S
    int* off        = hist + S;              // S+1
    int* cursor     = off + S + 1;           // S
    int* bsum       = cursor + S;            // NB
    int* bscan      = bsum + NB;             // NB
    int* dummy      = bscan + NB;            // 1
    int* sorted_src = dummy + 1;             // E
    size_t ofs = (size_t)((char*)(sorted_src + E) - (char*)d_ws);
    ofs = (ofs + 15) & ~(size_t)15;
    unsigned short* WlT = (unsigned short*)((char*)d_ws + ofs);   // 128*896
    float* bias_total = (float*)(WlT + D * KTOT);                 // 128
    size_t ofs2 = (size_t)((char*)(bias_total + D) - (char*)d_ws);
    ofs2 = (ofs2 + 15) & ~(size_t)15;
    unsigned short* Abuf = (unsigned short*)((char*)d_ws + ofs2); // Npad*896

    hipMemsetAsync(hist, 0, (size_t)S * sizeof(int), stream);

    int prep_total = 7 * D * D + D;
    prep_kernel<<<(prep_total + 255) / 256, 256, 0, stream>>>(W_l, W_r, b, emb, WlT, bias_total);

    hist_kernel<<<(E + 255) / 256, 256, 0, stream>>>(ei, et, hist, E);
    scan1_kernel<<<NB, 256, 0, stream>>>(hist, off, bsum, S);
    scan1_kernel<<<1, 256, 0, stream>>>(bsum, bscan, dummy, NB);
    scan3_kernel<<<NB, 256, 0, stream>>>(off, cursor, bscan, S, E);
    fill_kernel<<<(E + 255) / 256, 256, 0, stream>>>(ei, et, cursor, sorted_src, E);

    int tasks = S + N;
    aggregate_kernel<<<(tasks + 3) / 4, 256, 0, stream>>>(x, off, sorted_src, Abuf, S, N);

    gemm_ln_kernel<<<NBLK, 256, 0, stream>>>(Abuf, WlT, bias_total, gamma, beta,
                                             (float*)d_out, N);
}